// Round 12
// baseline (140.442 us; speedup 1.0000x reference)
//
#include <hip/hip_runtime.h>

#define NROWS 131072
#define D 64
#define K 1024

typedef __attribute__((ext_vector_type(8))) short short8;
typedef __attribute__((ext_vector_type(4))) float f32x4;
typedef unsigned int u32;

// ws layout (bytes):
//   [0, 131072)        ehT  ushort[1024][64]  bf16 codebook, [code][d]
//   [131072, 135168)   e2g  float[1024]       = -0.5*||e_k||^2
//   [135168, 139264)   hist int[1024]
//   [139264, 143360)   wavesum float[1024]  (one per score block)

__device__ __forceinline__ unsigned short f2bf_rne(float f) {
    u32 u = __float_as_uint(f);
    u += 0x7fff + ((u >> 16) & 1);   // round-to-nearest-even
    return (unsigned short)(u >> 16);
}

__device__ __forceinline__ float b2f(short s) {
    return __uint_as_float(((u32)(unsigned short)s) << 16);
}

// 16 blocks x 256 threads: block handles 64 codes, thread = (code, d-quarter).
__global__ __launch_bounds__(256) void prep_kernel(const float* __restrict__ E,
                                                   unsigned short* __restrict__ ehT,
                                                   float* __restrict__ e2g,
                                                   int* __restrict__ hist) {
    __shared__ float ps[4][64];
    const int lane = threadIdx.x & 63;          // code offset within block
    const int w = threadIdx.x >> 6;             // d-quarter 0..3
    const int k = blockIdx.x * 64 + lane;
    float s = 0.f;
#pragma unroll
    for (int half = 0; half < 2; ++half) {
        short8 h8;
#pragma unroll
        for (int j = 0; j < 8; ++j) {
            float v = E[(w * 16 + half * 8 + j) * K + k];   // coalesced across lanes
            s = fmaf(v, v, s);
            h8[j] = (short)f2bf_rne(v);
        }
        *(short8*)(ehT + (size_t)k * D + w * 16 + half * 8) = h8;
    }
    ps[w][lane] = s;
    __syncthreads();
    if (w == 0) e2g[k] = -0.5f * (ps[0][lane] + ps[1][lane] + ps[2][lane] + ps[3][lane]);
    if (threadIdx.x < 64) hist[blockIdx.x * 64 + threadIdx.x] = 0;
}

// R18: low-register restructure for real TLP. Evidence: VALU-busy ~15.5us is
// the largest pipe component but score sits at 49.6 (3.2x) with nothing else
// busy — whole-CU issue bubbles. Cause: ~112 regs/wave (64 arch + 48 AGPR
// persistent fragments) -> 4 waves/SIMD -> one 16-wave lockstep group/CU.
// Fix: ct-OUTER / t-INNER loop so only ONE code-tile (8 regs) + e2 (4) is
// live, software-pipelined 2-deep from the L2-resident codebook. The 48-reg
// persistent set disappears -> target ~64-80 total regs. Blocks shrink to
// 512 thr (8 waves), grid 1024 (128 rows/block, ONE chunk), LDS 25.7KB ->
// 3-4 INDEPENDENT barrier groups per CU; one group's staging/merge stalls
// hide under the others' compute. asm pointer-launder on the LDS base stops
// LICM from hoisting the (ct-invariant) b-reads into 64 registers.
// Numerics: per-score MFMA chain/operands/packed argmax bit-identical to
// R7/R17 -> same q/hist; only ls association changes (~1e-7). absmax canary:
// exactly 0.4326172.
__global__ __launch_bounds__(512) void score_kernel(const float* __restrict__ X,
                                                    const unsigned short* __restrict__ ehT,
                                                    const float* __restrict__ e2g,
                                                    int* __restrict__ hist,
                                                    float* __restrict__ wavesum,
                                                    float* __restrict__ q) {
    __shared__ unsigned short xbuf[8192];   // 16 KB: 128 rows x 64 d, frag order
    __shared__ float e2s[1024];             // -0.5||e||^2 (4 KB)
    __shared__ float mrg[128 * 9];          // per-row packed best per wave (stride 9)
    __shared__ int idxl[128];               // winning code per row
    __shared__ float redL[8];

    const int tid = threadIdx.x;            // 0..511
    const int wave = tid >> 6;              // 0..7
    const int lane = tid & 63;
    const int quad = lane >> 4;
    const int lc = lane & 15;
    const size_t row0 = (size_t)blockIdx.x * 128;

    // ---- stage 128 rows: 16B unit u = (t=u>>7, o=(u>>4)&7, ls=u&15) holds
    // bf16 X[t*16+ls][o*8..+8]; thread stages units {tid, tid+512}.
#pragma unroll
    for (int j = 0; j < 2; ++j) {
        int u = tid + j * 512;
        int tt = u >> 7, oo = (u >> 4) & 7, ll = u & 15;
        const float* xp = X + (row0 + (size_t)(tt * 16 + ll)) * D + oo * 8;
        float4 La = *(const float4*)(xp);
        float4 Lb = *(const float4*)(xp + 4);
        union { u32 uu[4]; short8 v; } pk;
        pk.uu[0] = __builtin_amdgcn_perm(__float_as_uint(La.y), __float_as_uint(La.x), 0x07060302);
        pk.uu[1] = __builtin_amdgcn_perm(__float_as_uint(La.w), __float_as_uint(La.z), 0x07060302);
        pk.uu[2] = __builtin_amdgcn_perm(__float_as_uint(Lb.y), __float_as_uint(Lb.x), 0x07060302);
        pk.uu[3] = __builtin_amdgcn_perm(__float_as_uint(Lb.w), __float_as_uint(Lb.z), 0x07060302);
        *(short8*)((char*)&xbuf[0] + u * 16) = pk.v;
    }
    e2s[tid] = e2g[tid];
    e2s[tid + 512] = e2g[tid + 512];

    // ---- wave owns codes [wave*128, +128) = 8 code-tiles, streamed 2-deep ----
    const int cbase = wave * 128;
    const unsigned short* ap = ehT + ((size_t)(cbase + lc) << 6) + quad * 8;  // +ct*1024 shorts/tile

    __syncthreads();   // B1: xbuf + e2s staged

    float bt8[8];
#pragma unroll
    for (int t = 0; t < 8; ++t) bt8[t] = -3.4e38f;

    // prologue of the ct pipeline
    short8 a0 = *(const short8*)(ap);
    short8 a1 = *(const short8*)(ap + 32);
    f32x4 ev2 = *(const f32x4*)(&e2s[cbase + quad * 4]);

#pragma unroll 1
    for (int ct = 0; ct < 8; ++ct) {
        short8 n0, n1;
        f32x4 en;
        if (ct < 7) {                       // prefetch next tile (L2-resident)
            const unsigned short* np = ap + (ct + 1) * 1024;
            n0 = *(const short8*)(np);
            n1 = *(const short8*)(np + 32);
            en = *(const f32x4*)(&e2s[cbase + (ct + 1) * 16 + quad * 4]);
        }
        const u32 cb = (u32)(cbase + ct * 16 + quad * 4);
        // launder the LDS base so LICM can't hoist the (ct-invariant) b-reads
        const char* bb = (const char*)&xbuf[0];
        asm volatile("" : "+v"(bb));
#pragma unroll
        for (int t = 0; t < 8; ++t) {
            const char* bp = bb + t * 2048 + quad * 256 + lc * 16;
            short8 b0 = *(const short8*)(bp);           // ks0: row t*16+lc, d quad*8..+8
            short8 b1 = *(const short8*)(bp + 1024);    // ks1
            f32x4 acc = __builtin_amdgcn_mfma_f32_16x16x32_bf16(a0, b0, ev2, 0, 0, 0);
            acc = __builtin_amdgcn_mfma_f32_16x16x32_bf16(a1, b1, acc, 0, 0, 0);
            // acc[r] = score(code = cb + r, xrow = t*16+lc); pack (score|code)
            float p0 = __uint_as_float((__float_as_uint(acc[0]) & 0xFFFFFC00u) | (cb + 0));
            float p1 = __uint_as_float((__float_as_uint(acc[1]) & 0xFFFFFC00u) | (cb + 1));
            float p2 = __uint_as_float((__float_as_uint(acc[2]) & 0xFFFFFC00u) | (cb + 2));
            float p3 = __uint_as_float((__float_as_uint(acc[3]) & 0xFFFFFC00u) | (cb + 3));
            float bt = bt8[t];
            bt = fmaxf(bt, fmaxf(p0, p1));   // v_max3
            bt = fmaxf(bt, fmaxf(p2, p3));   // v_max3
            bt8[t] = bt;
        }
        a0 = n0; a1 = n1; ev2 = en;
    }

    // ---- batched cross-lane reduce: 8 independent shfl chains ----
#pragma unroll
    for (int t = 0; t < 8; ++t) {
        float bt = bt8[t];
        bt = fmaxf(bt, __shfl_xor(bt, 16, 64));
        bt = fmaxf(bt, __shfl_xor(bt, 32, 64));
        if (lane < 16) mrg[(t * 16 + lane) * 9 + wave] = bt;
    }
    __syncthreads();   // B2: mrg visible

    // ---- merge across 8 waves (128 threads) ----
    if (tid < 128) {
        float m = mrg[tid * 9];
#pragma unroll
        for (int w = 1; w < 8; ++w) m = fmaxf(m, mrg[tid * 9 + w]);
        idxl[tid] = (int)(__float_as_uint(m) & 1023u);
    }
    __syncthreads();   // B3: idxl visible

    // ---- hist atomics fire-and-forget (drained by kernel end) ----
    if (tid < 128) atomicAdd(&hist[idxl[tid]], 1);

    // ---- fused epilogue: own staged slices; q = e_bf16; no X re-read ----
    float ls = 0.f;
#pragma unroll
    for (int j = 0; j < 2; ++j) {
        int u = tid + j * 512;
        int rowl = ((u >> 7) << 4) + (u & 15), so = (u >> 4) & 7;
        int kk = idxl[rowl];                       // broadcast among 8 so-threads
        short8 ev = *(const short8*)(ehT + ((size_t)kk << 6) + so * 8);
        short8 xv = *(const short8*)(&xbuf[u * 8]);
        float4 qa, qb;
        float e0, dd;
        e0 = b2f(ev[0]); dd = e0 - b2f(xv[0]); ls = fmaf(dd, dd, ls); qa.x = e0;
        e0 = b2f(ev[1]); dd = e0 - b2f(xv[1]); ls = fmaf(dd, dd, ls); qa.y = e0;
        e0 = b2f(ev[2]); dd = e0 - b2f(xv[2]); ls = fmaf(dd, dd, ls); qa.z = e0;
        e0 = b2f(ev[3]); dd = e0 - b2f(xv[3]); ls = fmaf(dd, dd, ls); qa.w = e0;
        e0 = b2f(ev[4]); dd = e0 - b2f(xv[4]); ls = fmaf(dd, dd, ls); qb.x = e0;
        e0 = b2f(ev[5]); dd = e0 - b2f(xv[5]); ls = fmaf(dd, dd, ls); qb.y = e0;
        e0 = b2f(ev[6]); dd = e0 - b2f(xv[6]); ls = fmaf(dd, dd, ls); qb.z = e0;
        e0 = b2f(ev[7]); dd = e0 - b2f(xv[7]); ls = fmaf(dd, dd, ls); qb.w = e0;
        float* qp = q + (row0 + (size_t)rowl) * D + so * 8;
        *(float4*)(qp) = qa;
        *(float4*)(qp + 4) = qb;
    }

    // ---- block loss reduction ----
    for (int off = 32; off > 0; off >>= 1) ls += __shfl_down(ls, off, 64);
    if (lane == 0) redL[wave] = ls;
    __syncthreads();
    if (tid == 0) {
        float L = 0.f;
#pragma unroll
        for (int i = 0; i < 8; ++i) L += redL[i];
        wavesum[blockIdx.x] = L;
    }
}

__global__ __launch_bounds__(1024) void finalize_kernel(const int* __restrict__ hist,
                                                        const float* __restrict__ wavesum,
                                                        float* __restrict__ out) {
    __shared__ float redH[16], redL[16];
    int tid = threadIdx.x;
    float p = (float)hist[tid] * (1.0f / (float)NROWS);
    float term = p * logf(p + 1e-10f);
    float ls = wavesum[tid];
    for (int off = 32; off > 0; off >>= 1) {
        term += __shfl_down(term, off, 64);
        ls += __shfl_down(ls, off, 64);
    }
    int lane = tid & 63, wid = tid >> 6;
    if (lane == 0) { redH[wid] = term; redL[wid] = ls; }
    __syncthreads();
    if (tid == 0) {
        float H = 0.f, L = 0.f;
#pragma unroll
        for (int i = 0; i < 16; ++i) { H += redH[i]; L += redL[i]; }
        out[(size_t)NROWS * D + 0] = 2.0f * (L / (float)(NROWS * D));
        out[(size_t)NROWS * D + 1] = expf(-H);
    }
}

extern "C" void kernel_launch(void* const* d_in, const int* in_sizes, int n_in,
                              void* d_out, int out_size, void* d_ws, size_t ws_size,
                              hipStream_t stream) {
    const float* X = (const float*)d_in[0];   // [64,2048,64] fp32
    const float* E = (const float*)d_in[1];   // [64,1024]   fp32
    float* out = (float*)d_out;

    char* w = (char*)d_ws;
    unsigned short* ehT = (unsigned short*)(w + 0);
    float* e2g          = (float*)(w + 131072);
    int* hist           = (int*)(w + 135168);
    float* wavesum      = (float*)(w + 139264);

    prep_kernel<<<16, 256, 0, stream>>>(E, ehT, e2g, hist);
    score_kernel<<<NROWS / 128, 512, 0, stream>>>(X, ehT, e2g, hist, wavesum, out);
    finalize_kernel<<<1, 1024, 0, stream>>>(hist, wavesum, out);
}

// Round 14
// 124.106 us; speedup vs baseline: 1.1316x; 1.1316x over previous
//
#include <hip/hip_runtime.h>

#define NROWS 131072
#define D 64
#define K 1024

typedef __attribute__((ext_vector_type(8))) short short8;
typedef __attribute__((ext_vector_type(4))) float f32x4;
typedef unsigned int u32;

// ws layout (bytes):
//   [0, 131072)        ehT  ushort[1024][64]  bf16 codebook, [code][d]
//   [131072, 135168)   e2g  float[1024]       = -0.5*||e_k||^2
//   [135168, 139264)   hist int[1024]
//   [139264, 143360)   wavesum float[256]  (one per score block)

__device__ __forceinline__ unsigned short f2bf_rne(float f) {
    u32 u = __float_as_uint(f);
    u += 0x7fff + ((u >> 16) & 1);   // round-to-nearest-even
    return (unsigned short)(u >> 16);
}

__device__ __forceinline__ float b2f(short s) {
    return __uint_as_float(((u32)(unsigned short)s) << 16);
}

// 16 blocks x 256 threads: block handles 64 codes, thread = (code, d-quarter).
__global__ __launch_bounds__(256) void prep_kernel(const float* __restrict__ E,
                                                   unsigned short* __restrict__ ehT,
                                                   float* __restrict__ e2g,
                                                   int* __restrict__ hist) {
    __shared__ float ps[4][64];
    const int lane = threadIdx.x & 63;          // code offset within block
    const int w = threadIdx.x >> 6;             // d-quarter 0..3
    const int k = blockIdx.x * 64 + lane;
    float s = 0.f;
#pragma unroll
    for (int half = 0; half < 2; ++half) {
        short8 h8;
#pragma unroll
        for (int j = 0; j < 8; ++j) {
            float v = E[(w * 16 + half * 8 + j) * K + k];   // coalesced across lanes
            s = fmaf(v, v, s);
            h8[j] = (short)f2bf_rne(v);
        }
        *(short8*)(ehT + (size_t)k * D + w * 16 + half * 8) = h8;
    }
    ps[w][lane] = s;
    __syncthreads();
    if (w == 0) e2g[k] = -0.5f * (ps[0][lane] + ps[1][lane] + ps[2][lane] + ps[3][lane]);
    if (threadIdx.x < 64) hist[blockIdx.x * 64 + threadIdx.x] = 0;
}

// R20 = R7 verbatim (best verified: total 122.05us, score 49.3us) — final
// bank after two container failures on the fused-finalize variant (lever
// retired; cannot distinguish kernel-induced crash from infra, EV of a third
// try is negative).
// SESSION LESSONS (banked in comments for future work):
//  - score floor ~49us across 8 structural families; occupancy pinned ~35%
//    regardless of block size/regs -> latency plateau, NOT a pipe roofline
//    (HBM 14%, MFMA 13%, VALU 31%).
//  - launch_bounds min-waves caps below the ~90-reg working set -> scratch
//    spill poison (R2-R4). nt-stores neutral (R17). ct-outer = 8x LDS traffic
//    regression (R18). Barrier halving/superchunks regress (R14).
//  - fused per-chunk epilogue (no X re-read, q = bf16 codebook row) and
//    batched shfl reduce are the two cuts that stuck (R13/R7).
// Numerics: packed score|code argmax; absmax canary exactly 0.4326172.
__global__ __launch_bounds__(1024) void score_kernel(const float* __restrict__ X,
                                                     const unsigned short* __restrict__ ehT,
                                                     const float* __restrict__ e2g,
                                                     int* __restrict__ hist,
                                                     float* __restrict__ wavesum,
                                                     float* __restrict__ q) {
    __shared__ unsigned short xbuf[2][8192];   // 2 x 16 KB: 128 rows x 64 d, frag order
    __shared__ float mrg[2][128 * 17];         // per-row packed best per wave (stride 17)
    __shared__ int idxl[2][128];               // winning code per row, double-buffered
    __shared__ float redL[16];

    const int tid = threadIdx.x;
    const int wave = tid >> 6;
    const int lane = tid & 63;
    const int quad = lane >> 4;
    const int lc = lane & 15;
    const size_t row0 = (size_t)blockIdx.x * 512;

    // ---- stage mapping: thread n -> LDS 16B unit n = (t=n>>7, o=(n>>4)&7,
    // ls=n&15) holding bf16 X[t*16+ls][o*8..+8]; global read fully coalesced.
    const int st = tid >> 7, so = (tid >> 4) & 7, sl = tid & 15;
    const int rowl = st * 16 + sl;             // this thread's staged row (0..127)
    const float* sbase = X + (row0 + (size_t)rowl) * D + so * 8;

    // ---- prologue: stage chunk 0 ----
    {
        float4 La = *(const float4*)(sbase);
        float4 Lb = *(const float4*)(sbase + 4);
        union { u32 u[4]; short8 v; } pk;
        pk.u[0] = __builtin_amdgcn_perm(__float_as_uint(La.y), __float_as_uint(La.x), 0x07060302);
        pk.u[1] = __builtin_amdgcn_perm(__float_as_uint(La.w), __float_as_uint(La.z), 0x07060302);
        pk.u[2] = __builtin_amdgcn_perm(__float_as_uint(Lb.y), __float_as_uint(Lb.x), 0x07060302);
        pk.u[3] = __builtin_amdgcn_perm(__float_as_uint(Lb.w), __float_as_uint(Lb.z), 0x07060302);
        *(short8*)((char*)&xbuf[0][0] + tid * 16) = pk.v;
    }

    // ---- persistent codebook fragments: wave owns codes [wave*64, wave*64+64) ----
    const int cbase = wave * 64;
    short8 ae[4][2];      // [code-tile][kslice]: code=tile*16+lc, d=ks*32+quad*8..+8
    f32x4 e2f[4];         // -0.5||e||^2 for codes tile*16+quad*4..+4 (MFMA C operand)
#pragma unroll
    for (int ct = 0; ct < 4; ++ct) {
        const unsigned short* ap = ehT + ((size_t)(cbase + ct * 16 + lc) << 6) + quad * 8;
        ae[ct][0] = *(const short8*)(ap);
        ae[ct][1] = *(const short8*)(ap + 32);
        e2f[ct] = *(const f32x4*)(e2g + cbase + ct * 16 + quad * 4);
    }
    const u32 cb0 = (u32)(cbase + quad * 4);

    __syncthreads();   // B1: chunk 0 staged

    float ls = 0.f;
    for (int c = 0; c < 4; ++c) {
        const int cur = c & 1;
        // issue-early global loads for chunk c+1 (land during compute; the
        // vmcnt wait sits at the stage-write after B2, long past latency)
        float4 La, Lb;
        if (c < 3) {
            La = *(const float4*)(sbase + (c + 1) * 8192);
            Lb = *(const float4*)(sbase + (c + 1) * 8192 + 4);
        }

        // ---- compute chunk c: pure ds_read + MFMA + max3 into bt8 ----
        float bt8[8];
        const char* bb = (const char*)&xbuf[cur][0];
#pragma unroll 2
        for (int t = 0; t < 8; ++t) {
            const char* bp = bb + t * 2048 + quad * 256 + lc * 16;
            short8 b0 = *(const short8*)(bp);           // ks0
            short8 b1 = *(const short8*)(bp + 1024);    // ks1
            float bt = -3.4e38f;
#pragma unroll
            for (int ct = 0; ct < 4; ++ct) {
                f32x4 acc = __builtin_amdgcn_mfma_f32_16x16x32_bf16(ae[ct][0], b0, e2f[ct], 0, 0, 0);
                acc = __builtin_amdgcn_mfma_f32_16x16x32_bf16(ae[ct][1], b1, acc, 0, 0, 0);
                // acc[r] = score(code = cb0 + ct*16 + r, xrow = t*16+lc)
                float p0 = __uint_as_float((__float_as_uint(acc[0]) & 0xFFFFFC00u) | (cb0 + ct * 16 + 0));
                float p1 = __uint_as_float((__float_as_uint(acc[1]) & 0xFFFFFC00u) | (cb0 + ct * 16 + 1));
                float p2 = __uint_as_float((__float_as_uint(acc[2]) & 0xFFFFFC00u) | (cb0 + ct * 16 + 2));
                float p3 = __uint_as_float((__float_as_uint(acc[3]) & 0xFFFFFC00u) | (cb0 + ct * 16 + 3));
                bt = fmaxf(bt, fmaxf(p0, p1));   // v_max3
                bt = fmaxf(bt, fmaxf(p2, p3));   // v_max3
            }
            bt8[t] = bt;
        }
        // ---- batched cross-lane reduce: 8 independent shfl chains ----
#pragma unroll
        for (int t = 0; t < 8; ++t) {
            float bt = bt8[t];
            bt = fmaxf(bt, __shfl_xor(bt, 16, 64));
            bt = fmaxf(bt, __shfl_xor(bt, 32, 64));
            if (lane < 16) mrg[cur][(t * 16 + lane) * 17 + wave] = bt;
        }
        __syncthreads();   // B2: mrg[cur] visible

        // ---- merge (128 thr) ∥ stage-write c+1 (all) ----
        if (tid < 128) {
            float m = mrg[cur][tid * 17];
#pragma unroll
            for (int w = 1; w < 16; ++w) m = fmaxf(m, mrg[cur][tid * 17 + w]);
            int kk = (int)(__float_as_uint(m) & 1023u);
            idxl[cur][tid] = kk;
            atomicAdd(&hist[kk], 1);
        }
        if (c < 3) {
            union { u32 u[4]; short8 v; } pk;
            pk.u[0] = __builtin_amdgcn_perm(__float_as_uint(La.y), __float_as_uint(La.x), 0x07060302);
            pk.u[1] = __builtin_amdgcn_perm(__float_as_uint(La.w), __float_as_uint(La.z), 0x07060302);
            pk.u[2] = __builtin_amdgcn_perm(__float_as_uint(Lb.y), __float_as_uint(Lb.x), 0x07060302);
            pk.u[3] = __builtin_amdgcn_perm(__float_as_uint(Lb.w), __float_as_uint(Lb.z), 0x07060302);
            *(short8*)((char*)&xbuf[cur ^ 1][0] + tid * 16) = pk.v;
        }
        __syncthreads();   // B3: idxl[cur] + staged chunk visible

        // ---- fused epilogue chunk c: own staged slice; q = e_bf16; no X read.
        // Interleaves with the next chunk's compute (independent pipes).
        {
            int kk = idxl[cur][rowl];                 // broadcast among 8 so-threads
            short8 ev = *(const short8*)(ehT + ((size_t)kk << 6) + so * 8);
            short8 xv = *(const short8*)(&xbuf[cur][tid * 8]);
            float4 qa, qb;
            float e0, dd;
            e0 = b2f(ev[0]); dd = e0 - b2f(xv[0]); ls = fmaf(dd, dd, ls); qa.x = e0;
            e0 = b2f(ev[1]); dd = e0 - b2f(xv[1]); ls = fmaf(dd, dd, ls); qa.y = e0;
            e0 = b2f(ev[2]); dd = e0 - b2f(xv[2]); ls = fmaf(dd, dd, ls); qa.z = e0;
            e0 = b2f(ev[3]); dd = e0 - b2f(xv[3]); ls = fmaf(dd, dd, ls); qa.w = e0;
            e0 = b2f(ev[4]); dd = e0 - b2f(xv[4]); ls = fmaf(dd, dd, ls); qb.x = e0;
            e0 = b2f(ev[5]); dd = e0 - b2f(xv[5]); ls = fmaf(dd, dd, ls); qb.y = e0;
            e0 = b2f(ev[6]); dd = e0 - b2f(xv[6]); ls = fmaf(dd, dd, ls); qb.z = e0;
            e0 = b2f(ev[7]); dd = e0 - b2f(xv[7]); ls = fmaf(dd, dd, ls); qb.w = e0;
            float* qp = q + (row0 + (size_t)(c * 128 + rowl)) * D + so * 8;
            *(float4*)(qp) = qa;
            *(float4*)(qp + 4) = qb;
        }
    }

    // ---- block loss reduction ----
    for (int off = 32; off > 0; off >>= 1) ls += __shfl_down(ls, off, 64);
    if (lane == 0) redL[wave] = ls;
    __syncthreads();
    if (tid == 0) {
        float L = 0.f;
#pragma unroll
        for (int i = 0; i < 16; ++i) L += redL[i];
        wavesum[blockIdx.x] = L;
    }
}

__global__ __launch_bounds__(1024) void finalize_kernel(const int* __restrict__ hist,
                                                        const float* __restrict__ wavesum,
                                                        float* __restrict__ out) {
    __shared__ float redH[16], redL[16];
    int tid = threadIdx.x;
    float p = (float)hist[tid] * (1.0f / (float)NROWS);
    float term = p * logf(p + 1e-10f);
    float ls = (tid < 256) ? wavesum[tid] : 0.f;
    for (int off = 32; off > 0; off >>= 1) {
        term += __shfl_down(term, off, 64);
        ls += __shfl_down(ls, off, 64);
    }
    int lane = tid & 63, wid = tid >> 6;
    if (lane == 0) { redH[wid] = term; redL[wid] = ls; }
    __syncthreads();
    if (tid == 0) {
        float H = 0.f, L = 0.f;
#pragma unroll
        for (int i = 0; i < 16; ++i) { H += redH[i]; L += redL[i]; }
        out[(size_t)NROWS * D + 0] = 2.0f * (L / (float)(NROWS * D));
        out[(size_t)NROWS * D + 1] = expf(-H);
    }
}

extern "C" void kernel_launch(void* const* d_in, const int* in_sizes, int n_in,
                              void* d_out, int out_size, void* d_ws, size_t ws_size,
                              hipStream_t stream) {
    const float* X = (const float*)d_in[0];   // [64,2048,64] fp32
    const float* E = (const float*)d_in[1];   // [64,1024]   fp32
    float* out = (float*)d_out;

    char* w = (char*)d_ws;
    unsigned short* ehT = (unsigned short*)(w + 0);
    float* e2g          = (float*)(w + 131072);
    int* hist           = (int*)(w + 135168);
    float* wavesum      = (float*)(w + 139264);

    prep_kernel<<<16, 256, 0, stream>>>(E, ehT, e2g, hist);
    score_kernel<<<NROWS / 512, 1024, 0, stream>>>(X, ehT, e2g, hist, wavesum, out);
    finalize_kernel<<<1, 1024, 0, stream>>>(hist, wavesum, out);
}